// Round 3
// baseline (1230.912 us; speedup 1.0000x reference)
//
#include <hip/hip_runtime.h>
#include <hip/hip_bf16.h>

#define SEQ 2048
#define BSZ 2
#define DIM 1024
#define NH 16
#define HD 64
#define WIN 8
#define PN 256

typedef __hip_bfloat16 bf16;
typedef __attribute__((ext_vector_type(8))) short short8;
typedef __attribute__((ext_vector_type(4))) short short4v;
typedef __attribute__((ext_vector_type(4))) float f32x4;

__device__ __forceinline__ float b2f(bf16 x) { return __bfloat162float(x); }
__device__ __forceinline__ bf16 f2b(float x) { return __float2bfloat16(x); }
__device__ __forceinline__ short fbits(float x) { bf16 h = __float2bfloat16(x); return *(short*)&h; }

// ---------------------------------------------------------------------------
// phrase[p][b][d] = max_{w<8} query[(8p+w)][b][d]   (fp32 in, fp32 out)
// ---------------------------------------------------------------------------
__global__ void phrase_max_kernel(const float* __restrict__ q, float* __restrict__ phrase) {
    int idx = blockIdx.x * 256 + threadIdx.x;          // over P*B*D
    int d  = idx % DIM;
    int pb = idx / DIM;
    int b  = pb % BSZ;
    int p  = pb / BSZ;
    float m = -1e30f;
#pragma unroll
    for (int w = 0; w < WIN; ++w)
        m = fmaxf(m, q[((size_t)(p * WIN + w) * BSZ + b) * DIM + d]);
    phrase[idx] = m;
}

// ---------------------------------------------------------------------------
// gv[bh][p][d] = sum_j gauss(p,j) * v[bh][j][d], banded (|j-mu|<=15.5,
// truncation weight < 2e-14).  v, gv bf16.
// ---------------------------------------------------------------------------
__global__ void gauss_v_kernel(const bf16* __restrict__ v, bf16* __restrict__ gv) {
    int blk = blockIdx.x;                  // B*H*PN
    int p  = blk % PN;
    int bh = blk / PN;
    int lane = threadIdx.x;                // 64 = dim
    float mu = p * (float)WIN + (WIN - 1) * 0.5f;   // 8p + 3.5, sigma = 2
    float acc = 0.f;
    int j0 = p * WIN - 12;
#pragma unroll
    for (int jj = 0; jj < 32; ++jj) {
        int j = j0 + jj;
        if (j < 0 || j >= SEQ) continue;
        float dd = (float)j - mu;
        float w = __expf(-dd * dd * 0.125f) * 0.199471140200716f;  // 1/(sqrt(2pi)*2)
        acc += w * b2f(v[((size_t)bh * SEQ + j) * HD + lane]);
    }
    gv[((size_t)bh * PN + p) * HD + lane] = f2b(acc);
}

// ---------------------------------------------------------------------------
// C = (A(M,K) @ W(N,K)^T + bias) * scale.  A, W, bias fp32 in HBM; tiles are
// converted fp32->bf16 during LDS staging; accum fp32 via MFMA.
// mode 0: head-scatter bf16  C[((b*NH+h)*LEN + s)*HD + hd], m=s*BSZ+b, n=h*64+hd
// mode 1: direct fp32        C[m*DIM + n]
// 128x128 tile, BK=32, 4 waves each 64x64 via 4x4 mfma_f32_16x16x32_bf16.
// ---------------------------------------------------------------------------
__global__ __launch_bounds__(256) void gemm_bt(const float* __restrict__ A,
                                               const float* __restrict__ W,
                                               const float* __restrict__ bias,
                                               void* __restrict__ Cout,
                                               int M, int K, float scale,
                                               int mode, int LEN) {
    __shared__ bf16 As[128 * 32];
    __shared__ bf16 Ws[128 * 32];
    int t = threadIdx.x;
    int m0 = blockIdx.x * 128;
    int n0 = blockIdx.y * 128;
    int wave = t >> 6, lane = t & 63;
    int wm = (wave >> 1) * 64, wn = (wave & 1) * 64;
    int l15 = lane & 15, quad = lane >> 4;

    f32x4 acc[4][4] = {};

    for (int k0 = 0; k0 < K; k0 += 32) {
        // stage: 128 rows x 32 cols fp32 -> bf16. 1024 float4-chunks per matrix.
#pragma unroll
        for (int c = t; c < 1024; c += 256) {
            int r = c >> 3, o = (c & 7) * 4;
            f32x4 a4 = *(const f32x4*)(A + (size_t)(m0 + r) * K + k0 + o);
            f32x4 w4 = *(const f32x4*)(W + (size_t)(n0 + r) * K + k0 + o);
            short4v ap, wp;
#pragma unroll
            for (int e = 0; e < 4; ++e) { ap[e] = fbits(a4[e]); wp[e] = fbits(w4[e]); }
            *(short4v*)&As[r * 32 + o] = ap;
            *(short4v*)&Ws[r * 32 + o] = wp;
        }
        __syncthreads();
        short8 af[4], bfr[4];
#pragma unroll
        for (int tm = 0; tm < 4; ++tm)
            af[tm] = *(short8*)&As[(wm + tm * 16 + l15) * 32 + quad * 8];
#pragma unroll
        for (int tn = 0; tn < 4; ++tn)
            bfr[tn] = *(short8*)&Ws[(wn + tn * 16 + l15) * 32 + quad * 8];
#pragma unroll
        for (int tm = 0; tm < 4; ++tm)
#pragma unroll
            for (int tn = 0; tn < 4; ++tn)
                acc[tm][tn] = __builtin_amdgcn_mfma_f32_16x16x32_bf16(af[tm], bfr[tn], acc[tm][tn], 0, 0, 0);
        __syncthreads();
    }

    // epilogue: C/D layout col = lane&15, row = quad*4 + reg
#pragma unroll
    for (int tm = 0; tm < 4; ++tm) {
        int mrow = m0 + wm + tm * 16 + quad * 4;
#pragma unroll
        for (int tn = 0; tn < 4; ++tn) {
            int n = n0 + wn + tn * 16 + l15;
            float bsv = bias[n];
#pragma unroll
            for (int r = 0; r < 4; ++r) {
                int m = mrow + r;
                float val = (acc[tm][tn][r] + bsv) * scale;
                if (mode == 0) {
                    int s = m / BSZ, b = m % BSZ;
                    int h = n >> 6, hd = n & 63;
                    ((bf16*)Cout)[((size_t)(b * NH + h) * LEN + s) * HD + hd] = f2b(val);
                } else {
                    ((float*)Cout)[(size_t)m * DIM + n] = val;
                }
            }
        }
    }
}

// ---------------------------------------------------------------------------
// Fused attention (correctness-first): per (b,h), 64 query rows per block.
//   phase 0: gauss branch over PN phrase keys (q_g, k_g, gv)
//   phase 1: base branch over SEQ keys (q_b, k_b, v)
// result = 0.5 * sum_phase (sum_j exp(s_j) vrow_j) / (sum_j exp(s_j))
// No max-subtraction: |s| <= ~10 with correct upstream; exp clamped anyway.
// ---------------------------------------------------------------------------
__global__ __launch_bounds__(256) void attn_kernel(const bf16* __restrict__ qb,
                                                   const bf16* __restrict__ kb,
                                                   const bf16* __restrict__ vv,
                                                   const bf16* __restrict__ qg,
                                                   const bf16* __restrict__ kg,
                                                   const bf16* __restrict__ gv,
                                                   float* __restrict__ out) {
    __shared__ float Qs[64][65];   // [row][hd]
    __shared__ float Ks[64][65];   // [key][hd]
    __shared__ float Ps[64][65];   // [row][key]
    __shared__ bf16  Vs[64][66];   // [key][d]

    int t = threadIdx.x;
    int tx = t & 15, ty = t >> 4;      // 16x16 threads, each owns 4x4
    int q0 = blockIdx.x * 64;
    int bh = blockIdx.y;               // b*NH + h
    int b = bh / NH, h = bh % NH;

    float result[4][4] = {};

    for (int phase = 0; phase < 2; ++phase) {
        const bf16* qptr = phase ? qb : qg;
        const bf16* kptr = phase ? kb : kg;
        const bf16* vptr = phase ? vv : gv;
        int kvlen = phase ? SEQ : PN;

        // stage Q rows for this phase: 64 rows x 64 dims
        {
            int r = t >> 2, c0 = (t & 3) * 16;
            const bf16* src = qptr + ((size_t)bh * SEQ + q0 + r) * HD + c0;
#pragma unroll
            for (int e = 0; e < 16; ++e) Qs[r][c0 + e] = b2f(src[e]);
        }

        float outacc[4][4] = {};
        float l[4] = {};
        int nchunk = kvlen / 64;
        for (int ch = 0; ch < nchunk; ++ch) {
            int j0 = ch * 64;
            __syncthreads();   // Q staged (first iter) / prev PV reads done
            {
                int r = t >> 2, c0 = (t & 3) * 16;
                const bf16* ksrc = kptr + ((size_t)bh * kvlen + j0 + r) * HD + c0;
                const bf16* vsrc = vptr + ((size_t)bh * kvlen + j0 + r) * HD + c0;
#pragma unroll
                for (int e = 0; e < 16; ++e) Ks[r][c0 + e] = b2f(ksrc[e]);
#pragma unroll
                for (int e = 0; e < 16; ++e) Vs[r][c0 + e] = vsrc[e];
            }
            __syncthreads();
            // scores: 4 rows x 4 keys per thread
            float s[4][4] = {};
            for (int hd = 0; hd < HD; ++hd) {
                float qa[4], kv[4];
#pragma unroll
                for (int i = 0; i < 4; ++i) qa[i] = Qs[ty * 4 + i][hd];
#pragma unroll
                for (int j = 0; j < 4; ++j) kv[j] = Ks[tx * 4 + j][hd];
#pragma unroll
                for (int i = 0; i < 4; ++i)
#pragma unroll
                    for (int j = 0; j < 4; ++j) s[i][j] += qa[i] * kv[j];
            }
#pragma unroll
            for (int i = 0; i < 4; ++i)
#pragma unroll
                for (int j = 0; j < 4; ++j)
                    Ps[ty * 4 + i][tx * 4 + j] = __expf(fminf(s[i][j], 30.f));
            __syncthreads();   // Ps visible to all
            // PV: out[row][dim] += P[row][k] * V[k][dim]; l[row] += P[row][k]
            for (int k = 0; k < 64; ++k) {
#pragma unroll
                for (int i = 0; i < 4; ++i) {
                    float pa = Ps[ty * 4 + i][k];
                    l[i] += pa;
#pragma unroll
                    for (int j = 0; j < 4; ++j)
                        outacc[i][j] += pa * b2f(Vs[k][tx * 4 + j]);
                }
            }
        }
#pragma unroll
        for (int i = 0; i < 4; ++i) {
            float inv = 0.5f / fmaxf(l[i], 1e-20f);
#pragma unroll
            for (int j = 0; j < 4; ++j) result[i][j] += outacc[i][j] * inv;
        }
        __syncthreads();   // phase boundary: all PV reads done before restage
    }

    // store to attn_out (S, B, D) fp32
#pragma unroll
    for (int i = 0; i < 4; ++i) {
        int srow = q0 + ty * 4 + i;
#pragma unroll
        for (int j = 0; j < 4; ++j) {
            int dcol = h * HD + tx * 4 + j;
            out[((size_t)srow * BSZ + b) * DIM + dcol] = result[i][j];
        }
    }
}

// ---------------------------------------------------------------------------
extern "C" void kernel_launch(void* const* d_in, const int* in_sizes, int n_in,
                              void* d_out, int out_size, void* d_ws, size_t ws_size,
                              hipStream_t stream) {
    (void)in_sizes; (void)n_in; (void)out_size; (void)ws_size;
    const float* query = (const float*)d_in[0];
    const float* Wq_b  = (const float*)d_in[1];
    const float* bq_b  = (const float*)d_in[2];
    const float* Wk_b  = (const float*)d_in[3];
    const float* bk_b  = (const float*)d_in[4];
    const float* Wq_g  = (const float*)d_in[5];
    const float* bq_g  = (const float*)d_in[6];
    const float* Wk_g  = (const float*)d_in[7];
    const float* bk_g  = (const float*)d_in[8];
    const float* Wv    = (const float*)d_in[9];
    const float* bv    = (const float*)d_in[10];
    const float* Wo    = (const float*)d_in[11];
    const float* bo    = (const float*)d_in[12];
    float* out = (float*)d_out;

    const size_t NQ = (size_t)BSZ * NH * SEQ * HD;   // 4194304
    const size_t NP = (size_t)BSZ * NH * PN * HD;    // 524288
    bf16* q_b      = (bf16*)d_ws;
    bf16* k_b      = q_b + NQ;
    bf16* v_       = k_b + NQ;
    bf16* q_g      = v_ + NQ;
    bf16* k_g      = q_g + NQ;
    bf16* gv       = k_g + NP;
    float* phrase   = (float*)(gv + NP);             // 16B-aligned offset
    float* attn_out = phrase + (size_t)PN * BSZ * DIM;
    // total ws use: ~54 MB

    phrase_max_kernel<<<(PN * BSZ * DIM) / 256, 256, 0, stream>>>(query, phrase);

    dim3 g1((SEQ * BSZ) / 128, DIM / 128);
    gemm_bt<<<g1, 256, 0, stream>>>(query, Wq_b, bq_b, q_b, SEQ * BSZ, DIM, 0.125f, 0, SEQ);
    gemm_bt<<<g1, 256, 0, stream>>>(query, Wk_b, bk_b, k_b, SEQ * BSZ, DIM, 1.0f, 0, SEQ);
    gemm_bt<<<g1, 256, 0, stream>>>(query, Wv, bv, v_, SEQ * BSZ, DIM, 1.0f, 0, SEQ);
    gemm_bt<<<g1, 256, 0, stream>>>(query, Wq_g, bq_g, q_g, SEQ * BSZ, DIM, 0.125f, 0, SEQ);

    dim3 g2((PN * BSZ) / 128, DIM / 128);
    gemm_bt<<<g2, 256, 0, stream>>>(phrase, Wk_g, bk_g, k_g, PN * BSZ, DIM, 1.0f, 0, PN);

    gauss_v_kernel<<<BSZ * NH * PN, 64, 0, stream>>>(v_, gv);

    dim3 g3(SEQ / 64, BSZ * NH);
    attn_kernel<<<g3, 256, 0, stream>>>(q_b, k_b, v_, q_g, k_g, gv, attn_out);

    gemm_bt<<<g1, 256, 0, stream>>>(attn_out, Wo, bo, out, SEQ * BSZ, DIM, 1.0f, 1, SEQ);
}

// Round 4
// 614.679 us; speedup vs baseline: 2.0025x; 2.0025x over previous
//
#include <hip/hip_runtime.h>
#include <hip/hip_bf16.h>

#define SEQ 2048
#define BSZ 2
#define DIM 1024
#define NH 16
#define HD 64
#define WIN 8
#define PN 256

typedef __hip_bfloat16 bf16;
typedef __attribute__((ext_vector_type(8))) short short8;
typedef __attribute__((ext_vector_type(4))) short short4v;
typedef __attribute__((ext_vector_type(4))) float f32x4;

__device__ __forceinline__ float b2f(bf16 x) { return __bfloat162float(x); }
__device__ __forceinline__ bf16 f2b(float x) { return __float2bfloat16(x); }
__device__ __forceinline__ short fbits(float x) { bf16 h = __float2bfloat16(x); return *(short*)&h; }

// ---------------------------------------------------------------------------
// phrase[p][b][d] = max_{w<8} query[(8p+w)][b][d]   (fp32 in, fp32 out)
// ---------------------------------------------------------------------------
__global__ void phrase_max_kernel(const float* __restrict__ q, float* __restrict__ phrase) {
    int idx = blockIdx.x * 256 + threadIdx.x;          // over P*B*D
    int d  = idx % DIM;
    int pb = idx / DIM;
    int b  = pb % BSZ;
    int p  = pb / BSZ;
    float m = -1e30f;
#pragma unroll
    for (int w = 0; w < WIN; ++w)
        m = fmaxf(m, q[((size_t)(p * WIN + w) * BSZ + b) * DIM + d]);
    phrase[idx] = m;
}

// ---------------------------------------------------------------------------
// gvT[bh*HD+hd][p] = sum_j gauss(p,j) * vT[bh*HD+hd][j], banded |j-mu|<=15.5
// (truncation weight < 2e-14).  Transposed layouts on both sides.
// ---------------------------------------------------------------------------
__global__ void gauss_v_kernel(const bf16* __restrict__ vT, bf16* __restrict__ gvT) {
    int row = blockIdx.x;               // bh*HD + hd  (2048 rows)
    int p   = threadIdx.x;              // 0..255
    float mu = p * (float)WIN + (WIN - 1) * 0.5f;   // 8p + 3.5, sigma = 2
    float acc = 0.f;
    int j0 = p * WIN - 12;
    const bf16* src = vT + (size_t)row * SEQ;
#pragma unroll
    for (int jj = 0; jj < 32; ++jj) {
        int j = j0 + jj;
        if (j < 0 || j >= SEQ) continue;
        float dd = (float)j - mu;
        acc += __expf(-dd * dd * 0.125f) * 0.199471140200716f * b2f(src[j]);
    }
    gvT[(size_t)row * PN + p] = f2b(acc);
}

// ---------------------------------------------------------------------------
// C = (A(M,K) @ W(N,K)^T + bias) * scale.  A, W, bias fp32; fp32->bf16 during
// LDS staging; fp32 MFMA accum.
// mode 0: head-scatter bf16   C[((b*NH+h)*LEN + s)*HD + hd]
// mode 1: direct fp32         C[m*DIM + n]
// mode 2: transposed scatter  C[((b*NH+h)*HD + hd)*LEN + s]   (for V)
// 128x128 tile, BK=32, 4 waves each 64x64 via 4x4 mfma_f32_16x16x32_bf16.
// ---------------------------------------------------------------------------
__global__ __launch_bounds__(256) void gemm_bt(const float* __restrict__ A,
                                               const float* __restrict__ W,
                                               const float* __restrict__ bias,
                                               void* __restrict__ Cout,
                                               int M, int K, float scale,
                                               int mode, int LEN) {
    __shared__ bf16 As[128 * 32];
    __shared__ bf16 Ws[128 * 32];
    int t = threadIdx.x;
    int m0 = blockIdx.x * 128;
    int n0 = blockIdx.y * 128;
    int wave = t >> 6, lane = t & 63;
    int wm = (wave >> 1) * 64, wn = (wave & 1) * 64;
    int l15 = lane & 15, quad = lane >> 4;

    f32x4 acc[4][4] = {};

    for (int k0 = 0; k0 < K; k0 += 32) {
#pragma unroll
        for (int c = t; c < 1024; c += 256) {
            int r = c >> 3, o = (c & 7) * 4;
            f32x4 a4 = *(const f32x4*)(A + (size_t)(m0 + r) * K + k0 + o);
            f32x4 w4 = *(const f32x4*)(W + (size_t)(n0 + r) * K + k0 + o);
            short4v ap, wp;
#pragma unroll
            for (int e = 0; e < 4; ++e) { ap[e] = fbits(a4[e]); wp[e] = fbits(w4[e]); }
            *(short4v*)&As[r * 32 + o] = ap;
            *(short4v*)&Ws[r * 32 + o] = wp;
        }
        __syncthreads();
        short8 af[4], bfr[4];
#pragma unroll
        for (int tm = 0; tm < 4; ++tm)
            af[tm] = *(short8*)&As[(wm + tm * 16 + l15) * 32 + quad * 8];
#pragma unroll
        for (int tn = 0; tn < 4; ++tn)
            bfr[tn] = *(short8*)&Ws[(wn + tn * 16 + l15) * 32 + quad * 8];
#pragma unroll
        for (int tm = 0; tm < 4; ++tm)
#pragma unroll
            for (int tn = 0; tn < 4; ++tn)
                acc[tm][tn] = __builtin_amdgcn_mfma_f32_16x16x32_bf16(af[tm], bfr[tn], acc[tm][tn], 0, 0, 0);
        __syncthreads();
    }

#pragma unroll
    for (int tm = 0; tm < 4; ++tm) {
        int mrow = m0 + wm + tm * 16 + quad * 4;
#pragma unroll
        for (int tn = 0; tn < 4; ++tn) {
            int n = n0 + wn + tn * 16 + l15;
            float bsv = bias[n];
#pragma unroll
            for (int r = 0; r < 4; ++r) {
                int m = mrow + r;
                float val = (acc[tm][tn][r] + bsv) * scale;
                if (mode == 0) {
                    int s = m / BSZ, b = m % BSZ;
                    int h = n >> 6, hd = n & 63;
                    ((bf16*)Cout)[((size_t)(b * NH + h) * LEN + s) * HD + hd] = f2b(val);
                } else if (mode == 2) {
                    int s = m / BSZ, b = m % BSZ;
                    int h = n >> 6, hd = n & 63;
                    ((bf16*)Cout)[((size_t)(b * NH + h) * HD + hd) * LEN + s] = f2b(val);
                } else {
                    ((float*)Cout)[(size_t)m * DIM + n] = val;
                }
            }
        }
    }
}

// ---------------------------------------------------------------------------
// MFMA attention: per block (b,h) x 64 q-rows; 4 waves, one 16-row m-tile each.
//   phase 0: gauss branch over PN phrase keys (q_g, k_g, gvT)
//   phase 1: base branch over SEQ keys (q_b, k_b, vT)
// p = exp2(s) with log2e pre-folded into q scaling; l via ones-B-frag mfma
// (rowsum lands in same C-layout rows as O accumulator -> no cross-lane).
// result = 0.5 * sum_phase O/l.   attn_out fp32 (S,B,D).
// ---------------------------------------------------------------------------
__global__ __launch_bounds__(256) void attn_kernel(const bf16* __restrict__ qb,
                                                   const bf16* __restrict__ kb,
                                                   const bf16* __restrict__ vT,
                                                   const bf16* __restrict__ qg,
                                                   const bf16* __restrict__ kg,
                                                   const bf16* __restrict__ gvT,
                                                   float* __restrict__ out) {
    __shared__ bf16 Qs[64][72];    // [qrow][hd]
    __shared__ bf16 Ks[64][72];    // [key][hd]
    __shared__ bf16 Vt[64][72];    // [hd][key]   (staged from vT global)
    __shared__ bf16 Ps[64][72];    // [qrow][key] (C->A layout round-trip)

    int t = threadIdx.x;
    int wave = t >> 6, lane = t & 63;
    int l15 = lane & 15, quad = lane >> 4;
    int q0 = blockIdx.x * 64;
    int bh = blockIdx.y;               // b*NH + h
    int b = bh / NH, h = bh % NH;

    const short8 ones = (short8)0x3F80;   // bf16 1.0 splat

    float result[4][4] = {};              // [n-tile][row]

    for (int phase = 0; phase < 2; ++phase) {
        const bf16* qptr = phase ? qb : qg;
        const bf16* kptr = phase ? kb : kg;
        const bf16* vtp  = phase ? vT : gvT;
        int kvlen = phase ? SEQ : PN;

        __syncthreads();   // prior phase reads of Qs done
        {
            int r = t >> 2, c0 = (t & 3) * 16;
            const bf16* qsrc = qptr + ((size_t)bh * SEQ + q0 + r) * HD + c0;
            *(short8*)&Qs[r][c0]     = *(const short8*)qsrc;
            *(short8*)&Qs[r][c0 + 8] = *(const short8*)(qsrc + 8);
        }

        f32x4 o_acc[4] = {};
        f32x4 l_acc = {};
        int nchunk = kvlen / 64;
        for (int ch = 0; ch < nchunk; ++ch) {
            int j0 = ch * 64;
            __syncthreads();   // prev chunk's K/V reads done (and Q staged, 1st)
            {
                int r = t >> 2, c0 = (t & 3) * 16;
                const bf16* ksrc = kptr + ((size_t)bh * kvlen + j0 + r) * HD + c0;
                const bf16* vsrc = vtp + (size_t)(bh * HD + r) * kvlen + j0 + c0;
                *(short8*)&Ks[r][c0]     = *(const short8*)ksrc;
                *(short8*)&Ks[r][c0 + 8] = *(const short8*)(ksrc + 8);
                *(short8*)&Vt[r][c0]     = *(const short8*)vsrc;
                *(short8*)&Vt[r][c0 + 8] = *(const short8*)(vsrc + 8);
            }
            __syncthreads();

            // S = Q K^T for this wave's 16 rows x 64 keys
            f32x4 s_acc[4] = {};
#pragma unroll
            for (int kk = 0; kk < 2; ++kk) {
                short8 a = *(short8*)&Qs[wave * 16 + l15][kk * 32 + quad * 8];
#pragma unroll
                for (int tn = 0; tn < 4; ++tn) {
                    short8 bb = *(short8*)&Ks[tn * 16 + l15][kk * 32 + quad * 8];
                    s_acc[tn] = __builtin_amdgcn_mfma_f32_16x16x32_bf16(a, bb, s_acc[tn], 0, 0, 0);
                }
            }
            // P = exp2(S) (log2e folded upstream), C-layout write to Ps
#pragma unroll
            for (int tn = 0; tn < 4; ++tn)
#pragma unroll
                for (int r = 0; r < 4; ++r)
                    Ps[wave * 16 + quad * 4 + r][tn * 16 + l15] =
                        f2b(exp2f(fminf(s_acc[tn][r], 43.f)));
            // same-wave read-back (lgkmcnt handles visibility; no barrier)
#pragma unroll
            for (int kk = 0; kk < 2; ++kk) {
                short8 pa = *(short8*)&Ps[wave * 16 + l15][kk * 32 + quad * 8];
                l_acc = __builtin_amdgcn_mfma_f32_16x16x32_bf16(pa, ones, l_acc, 0, 0, 0);
#pragma unroll
                for (int tn = 0; tn < 4; ++tn) {
                    short8 vb = *(short8*)&Vt[tn * 16 + l15][kk * 32 + quad * 8];
                    o_acc[tn] = __builtin_amdgcn_mfma_f32_16x16x32_bf16(pa, vb, o_acc[tn], 0, 0, 0);
                }
            }
        }
#pragma unroll
        for (int r = 0; r < 4; ++r) {
            float inv = 0.5f / fmaxf(l_acc[r], 1e-30f);
#pragma unroll
            for (int tn = 0; tn < 4; ++tn)
                result[tn][r] += o_acc[tn][r] * inv;
        }
    }

    // store attn_out (S,B,D) fp32; C-layout rows quad*4+r, cols tn*16+l15
#pragma unroll
    for (int r = 0; r < 4; ++r) {
        int srow = q0 + wave * 16 + quad * 4 + r;
#pragma unroll
        for (int tn = 0; tn < 4; ++tn) {
            int dcol = h * HD + tn * 16 + l15;
            out[((size_t)srow * BSZ + b) * DIM + dcol] = result[tn][r];
        }
    }
}

// ---------------------------------------------------------------------------
extern "C" void kernel_launch(void* const* d_in, const int* in_sizes, int n_in,
                              void* d_out, int out_size, void* d_ws, size_t ws_size,
                              hipStream_t stream) {
    (void)in_sizes; (void)n_in; (void)out_size; (void)ws_size;
    const float* query = (const float*)d_in[0];
    const float* Wq_b  = (const float*)d_in[1];
    const float* bq_b  = (const float*)d_in[2];
    const float* Wk_b  = (const float*)d_in[3];
    const float* bk_b  = (const float*)d_in[4];
    const float* Wq_g  = (const float*)d_in[5];
    const float* bq_g  = (const float*)d_in[6];
    const float* Wk_g  = (const float*)d_in[7];
    const float* bk_g  = (const float*)d_in[8];
    const float* Wv    = (const float*)d_in[9];
    const float* bv    = (const float*)d_in[10];
    const float* Wo    = (const float*)d_in[11];
    const float* bo    = (const float*)d_in[12];
    float* out = (float*)d_out;

    const size_t NQ = (size_t)BSZ * NH * SEQ * HD;   // 4194304
    const size_t NP = (size_t)BSZ * NH * PN * HD;    // 524288
    bf16* q_b      = (bf16*)d_ws;
    bf16* k_b      = q_b + NQ;
    bf16* vT       = k_b + NQ;        // [bh][hd][s]
    bf16* q_g      = vT + NQ;
    bf16* k_g      = q_g + NQ;
    bf16* gvT      = k_g + NP;        // [bh][hd][p]
    float* phrase   = (float*)(gvT + NP);
    float* attn_out = phrase + (size_t)PN * BSZ * DIM;
    // total ws use: ~54 MB

    const float QSCALE = 0.125f * 1.44269504088896f;  // fold log2(e) for exp2

    phrase_max_kernel<<<(PN * BSZ * DIM) / 256, 256, 0, stream>>>(query, phrase);

    dim3 g1((SEQ * BSZ) / 128, DIM / 128);
    gemm_bt<<<g1, 256, 0, stream>>>(query, Wq_b, bq_b, q_b, SEQ * BSZ, DIM, QSCALE, 0, SEQ);
    gemm_bt<<<g1, 256, 0, stream>>>(query, Wk_b, bk_b, k_b, SEQ * BSZ, DIM, 1.0f, 0, SEQ);
    gemm_bt<<<g1, 256, 0, stream>>>(query, Wv, bv, vT, SEQ * BSZ, DIM, 1.0f, 2, SEQ);
    gemm_bt<<<g1, 256, 0, stream>>>(query, Wq_g, bq_g, q_g, SEQ * BSZ, DIM, QSCALE, 0, SEQ);

    dim3 g2((PN * BSZ) / 128, DIM / 128);
    gemm_bt<<<g2, 256, 0, stream>>>(phrase, Wk_g, bk_g, k_g, PN * BSZ, DIM, 1.0f, 0, PN);

    gauss_v_kernel<<<BSZ * NH * HD, PN, 0, stream>>>(vT, gvT);

    dim3 g3(SEQ / 64, BSZ * NH);
    attn_kernel<<<g3, 256, 0, stream>>>(q_b, k_b, vT, q_g, k_g, gvT, attn_out);

    gemm_bt<<<g1, 256, 0, stream>>>(attn_out, Wo, bo, out, SEQ * BSZ, DIM, 1.0f, 1, SEQ);
}

// Round 5
// 298.294 us; speedup vs baseline: 4.1265x; 2.0606x over previous
//
#include <hip/hip_runtime.h>
#include <hip/hip_bf16.h>

#define SEQ 2048
#define BSZ 2
#define DIM 1024
#define NH 16
#define HD 64
#define WIN 8
#define PN 256

typedef __hip_bfloat16 bf16;
typedef __attribute__((ext_vector_type(8))) short short8;
typedef __attribute__((ext_vector_type(4))) float f32x4;

__device__ __forceinline__ float b2f(bf16 x) { return __bfloat162float(x); }
__device__ __forceinline__ bf16 f2b(float x) { return __float2bfloat16(x); }
__device__ __forceinline__ short fbits(float x) { bf16 h = __float2bfloat16(x); return *(short*)&h; }

// async global->LDS, 16B per lane; LDS dest must be wave-uniform base + lane*16
__device__ __forceinline__ void gl_lds16(const bf16* g, bf16* l) {
    __builtin_amdgcn_global_load_lds((const __attribute__((address_space(1))) void*)g,
                                     (__attribute__((address_space(3))) void*)l, 16, 0, 0);
}

// ---------------------------------------------------------------------------
// fp32 -> bf16 pre-convert: query (4M elems) + 6 weight matrices (6M elems)
// ---------------------------------------------------------------------------
__global__ void convert_kernel(const float* __restrict__ q,
                               const float* __restrict__ w0, const float* __restrict__ w1,
                               const float* __restrict__ w2, const float* __restrict__ w3,
                               const float* __restrict__ w4, const float* __restrict__ w5,
                               bf16* __restrict__ qbf, bf16* __restrict__ wbf) {
    int i = blockIdx.x * 256 + threadIdx.x;          // vector idx, 8 floats each
    const int QV = (SEQ * BSZ * DIM) / 8;            // 524288
    const int WV = (DIM * DIM) / 8;                  // 131072
    const float* src;
    bf16* dst;
    size_t off;
    if (i < QV) { src = q; dst = qbf; off = (size_t)i * 8; }
    else {
        int j = i - QV;
        int mat = j / WV, k = j - mat * WV;
        src = (mat == 0) ? w0 : (mat == 1) ? w1 : (mat == 2) ? w2
            : (mat == 3) ? w3 : (mat == 4) ? w4 : w5;
        dst = wbf + (size_t)mat * DIM * DIM;
        off = (size_t)k * 8;
    }
    f32x4 a = *(const f32x4*)(src + off);
    f32x4 b4 = *(const f32x4*)(src + off + 4);
    short8 o;
#pragma unroll
    for (int e = 0; e < 4; ++e) { o[e] = fbits(a[e]); o[e + 4] = fbits(b4[e]); }
    *(short8*)(dst + off) = o;
}

__global__ void bias_pack_kernel(const float* __restrict__ b0, const float* __restrict__ b1,
                                 const float* __restrict__ b2, const float* __restrict__ b3,
                                 const float* __restrict__ b4, const float* __restrict__ b5,
                                 float* __restrict__ bp) {
    int i = blockIdx.x * 256 + threadIdx.x;          // 6144
    int mat = i >> 10, k = i & 1023;
    const float* s = (mat == 0) ? b0 : (mat == 1) ? b1 : (mat == 2) ? b2
                   : (mat == 3) ? b3 : (mat == 4) ? b4 : b5;
    bp[i] = s[k];
}

// ---------------------------------------------------------------------------
// phrase[(p*BSZ+b)*DIM+d] = max_{w<8} query[(8p+w)][b][d]   (fp32 in, bf16 out)
// ---------------------------------------------------------------------------
__global__ void phrase_max_kernel(const float* __restrict__ q, bf16* __restrict__ phrase) {
    int idx = blockIdx.x * 256 + threadIdx.x;        // over P*B*D
    int d  = idx % DIM;
    int pb = idx / DIM;
    int b  = pb % BSZ;
    int p  = pb / BSZ;
    float m = -1e30f;
#pragma unroll
    for (int w = 0; w < WIN; ++w)
        m = fmaxf(m, q[((size_t)(p * WIN + w) * BSZ + b) * DIM + d]);
    phrase[idx] = f2b(m);
}

// ---------------------------------------------------------------------------
// gvT[bh*HD+hd][p] = sum_j gauss(p,j) * vT[bh*HD+hd][j], banded |j-mu|<=15.5
// ---------------------------------------------------------------------------
__global__ void gauss_v_kernel(const bf16* __restrict__ vT, bf16* __restrict__ gvT) {
    int row = blockIdx.x;               // bh*HD + hd  (2048 rows)
    int p   = threadIdx.x;              // 0..255
    float mu = p * (float)WIN + (WIN - 1) * 0.5f;
    float acc = 0.f;
    int j0 = p * WIN - 12;
    const bf16* src = vT + (size_t)row * SEQ;
#pragma unroll
    for (int jj = 0; jj < 32; ++jj) {
        int j = j0 + jj;
        if (j < 0 || j >= SEQ) continue;
        float dd = (float)j - mu;
        acc += __expf(-dd * dd * 0.125f) * 0.199471140200716f * b2f(src[j]);
    }
    gvT[(size_t)row * PN + p] = f2b(acc);
}

// ---------------------------------------------------------------------------
// Shared GEMM body: C = (A(M,K=1024) @ W(128-tile)^T + bias) * scale
// bf16 in via global_load_lds(16B), fp32 MFMA accum.  LDS [128][32] unpadded
// (m97 layout).  Epilogue modes: 0 head-scatter bf16, 1 direct fp32,
// 2 transposed head-scatter bf16 (for V).
// ---------------------------------------------------------------------------
__device__ __forceinline__ void gemm_body(const bf16* __restrict__ A,
                                          const bf16* __restrict__ W,
                                          const float* __restrict__ bias,
                                          void* __restrict__ Cout,
                                          int m0, int n0, float scale,
                                          int mode, int LEN) {
    __shared__ bf16 As[128 * 32];
    __shared__ bf16 Ws[128 * 32];
    int t = threadIdx.x;
    int wave = t >> 6, lane = t & 63;
    int wm = (wave >> 1) * 64, wn = (wave & 1) * 64;
    int l15 = lane & 15, quad = lane >> 4;

    f32x4 acc[4][4] = {};

    for (int k0 = 0; k0 < DIM; k0 += 32) {
        // chunk c covers row c>>2, elems (c&3)*8..+7 ; c = t and t+256
        {
            int c0 = t, c1 = t + 256;
            gl_lds16(A + (size_t)(m0 + (c0 >> 2)) * DIM + k0 + (c0 & 3) * 8, &As[c0 * 8]);
            gl_lds16(A + (size_t)(m0 + (c1 >> 2)) * DIM + k0 + (c1 & 3) * 8, &As[c1 * 8]);
            gl_lds16(W + (size_t)(n0 + (c0 >> 2)) * DIM + k0 + (c0 & 3) * 8, &Ws[c0 * 8]);
            gl_lds16(W + (size_t)(n0 + (c1 >> 2)) * DIM + k0 + (c1 & 3) * 8, &Ws[c1 * 8]);
        }
        __syncthreads();
        short8 af[4], bfr[4];
#pragma unroll
        for (int tm = 0; tm < 4; ++tm)
            af[tm] = *(short8*)&As[(wm + tm * 16 + l15) * 32 + quad * 8];
#pragma unroll
        for (int tn = 0; tn < 4; ++tn)
            bfr[tn] = *(short8*)&Ws[(wn + tn * 16 + l15) * 32 + quad * 8];
#pragma unroll
        for (int tm = 0; tm < 4; ++tm)
#pragma unroll
            for (int tn = 0; tn < 4; ++tn)
                acc[tm][tn] = __builtin_amdgcn_mfma_f32_16x16x32_bf16(af[tm], bfr[tn], acc[tm][tn], 0, 0, 0);
        __syncthreads();
    }

#pragma unroll
    for (int tm = 0; tm < 4; ++tm) {
        int mrow = m0 + wm + tm * 16 + quad * 4;
#pragma unroll
        for (int tn = 0; tn < 4; ++tn) {
            int n = n0 + wn + tn * 16 + l15;
            float bsv = bias[n];
#pragma unroll
            for (int r = 0; r < 4; ++r) {
                int m = mrow + r;
                float val = (acc[tm][tn][r] + bsv) * scale;
                if (mode == 0) {
                    int s = m / BSZ, b = m % BSZ;
                    int h = n >> 6, hd = n & 63;
                    ((bf16*)Cout)[((size_t)(b * NH + h) * LEN + s) * HD + hd] = f2b(val);
                } else if (mode == 2) {
                    int s = m / BSZ, b = m % BSZ;
                    int h = n >> 6, hd = n & 63;
                    ((bf16*)Cout)[((size_t)(b * NH + h) * HD + hd) * LEN + s] = f2b(val);
                } else {
                    ((float*)Cout)[(size_t)m * DIM + n] = val;
                }
            }
        }
    }
}

#define QSCALE (0.125f * 1.44269504088896f)   // fold log2(e) for exp2

// batched projections: z = 0:q_b 1:k_b 2:vT 3:q_g 4:k_g(phrase)
__global__ __launch_bounds__(256) void gemm_proj(const bf16* __restrict__ qbf,
                                                 const bf16* __restrict__ phrasebf,
                                                 const bf16* __restrict__ wbf,
                                                 const float* __restrict__ bias_pack,
                                                 bf16* __restrict__ q_b, bf16* __restrict__ k_b,
                                                 bf16* __restrict__ vT, bf16* __restrict__ q_g,
                                                 bf16* __restrict__ k_g) {
    int z = blockIdx.z;
    const bf16* A = qbf;
    bf16* C;
    int mode = 0, LEN = SEQ;
    float scale = 1.0f;
    switch (z) {
        case 0: C = q_b; scale = QSCALE; break;
        case 1: C = k_b; break;
        case 2: C = vT; mode = 2; break;
        case 3: C = q_g; scale = QSCALE; break;
        default:
            if (blockIdx.x >= 4) return;          // M = 512 for phrase GEMM
            A = phrasebf; C = k_g; LEN = PN; break;
    }
    gemm_body(A, wbf + (size_t)z * DIM * DIM, bias_pack + z * DIM, C,
              blockIdx.x * 128, blockIdx.y * 128, scale, mode, LEN);
}

// final: out = attn_bf @ Wo^T + bo   (fp32 out)
__global__ __launch_bounds__(256) void gemm_final(const bf16* __restrict__ attn_bf,
                                                  const bf16* __restrict__ wbf,
                                                  const float* __restrict__ bias_pack,
                                                  float* __restrict__ out) {
    gemm_body(attn_bf, wbf + (size_t)5 * DIM * DIM, bias_pack + 5 * DIM, out,
              blockIdx.x * 128, blockIdx.y * 128, 1.0f, 1, SEQ);
}

// ---------------------------------------------------------------------------
// MFMA attention (round-4 verified): per block (b,h) x 64 q-rows, 4 waves.
//   phase 0: gauss branch over PN phrase keys; phase 1: base over SEQ keys.
// Writes attn_bf bf16 [m=s*BSZ+b][h*64+hd].
// ---------------------------------------------------------------------------
__global__ __launch_bounds__(256) void attn_kernel(const bf16* __restrict__ qb,
                                                   const bf16* __restrict__ kb,
                                                   const bf16* __restrict__ vT,
                                                   const bf16* __restrict__ qg,
                                                   const bf16* __restrict__ kg,
                                                   const bf16* __restrict__ gvT,
                                                   bf16* __restrict__ out) {
    __shared__ bf16 Qs[64][72];    // [qrow][hd]
    __shared__ bf16 Ks[64][72];    // [key][hd]
    __shared__ bf16 Vt[64][72];    // [hd][key]
    __shared__ bf16 Ps[64][72];    // [qrow][key]

    int t = threadIdx.x;
    int wave = t >> 6, lane = t & 63;
    int l15 = lane & 15, quad = lane >> 4;
    int q0 = blockIdx.x * 64;
    int bh = blockIdx.y;
    int b = bh / NH, h = bh % NH;

    const short8 ones = (short8)0x3F80;   // bf16 1.0 splat

    float result[4][4] = {};              // [n-tile][row]

    for (int phase = 0; phase < 2; ++phase) {
        const bf16* qptr = phase ? qb : qg;
        const bf16* kptr = phase ? kb : kg;
        const bf16* vtp  = phase ? vT : gvT;
        int kvlen = phase ? SEQ : PN;

        __syncthreads();
        {
            int r = t >> 2, c0 = (t & 3) * 16;
            const bf16* qsrc = qptr + ((size_t)bh * SEQ + q0 + r) * HD + c0;
            *(short8*)&Qs[r][c0]     = *(const short8*)qsrc;
            *(short8*)&Qs[r][c0 + 8] = *(const short8*)(qsrc + 8);
        }

        f32x4 o_acc[4] = {};
        f32x4 l_acc = {};
        int nchunk = kvlen / 64;
        for (int ch = 0; ch < nchunk; ++ch) {
            int j0 = ch * 64;
            __syncthreads();
            {
                int r = t >> 2, c0 = (t & 3) * 16;
                const bf16* ksrc = kptr + ((size_t)bh * kvlen + j0 + r) * HD + c0;
                const bf16* vsrc = vtp + (size_t)(bh * HD + r) * kvlen + j0 + c0;
                *(short8*)&Ks[r][c0]     = *(const short8*)ksrc;
                *(short8*)&Ks[r][c0 + 8] = *(const short8*)(ksrc + 8);
                *(short8*)&Vt[r][c0]     = *(const short8*)vsrc;
                *(short8*)&Vt[r][c0 + 8] = *(const short8*)(vsrc + 8);
            }
            __syncthreads();

            f32x4 s_acc[4] = {};
#pragma unroll
            for (int kk = 0; kk < 2; ++kk) {
                short8 a = *(short8*)&Qs[wave * 16 + l15][kk * 32 + quad * 8];
#pragma unroll
                for (int tn = 0; tn < 4; ++tn) {
                    short8 bb = *(short8*)&Ks[tn * 16 + l15][kk * 32 + quad * 8];
                    s_acc[tn] = __builtin_amdgcn_mfma_f32_16x16x32_bf16(a, bb, s_acc[tn], 0, 0, 0);
                }
            }
#pragma unroll
            for (int tn = 0; tn < 4; ++tn)
#pragma unroll
                for (int r = 0; r < 4; ++r)
                    Ps[wave * 16 + quad * 4 + r][tn * 16 + l15] =
                        f2b(exp2f(fminf(s_acc[tn][r], 43.f)));
#pragma unroll
            for (int kk = 0; kk < 2; ++kk) {
                short8 pa = *(short8*)&Ps[wave * 16 + l15][kk * 32 + quad * 8];
                l_acc = __builtin_amdgcn_mfma_f32_16x16x32_bf16(pa, ones, l_acc, 0, 0, 0);
#pragma unroll
                for (int tn = 0; tn < 4; ++tn) {
                    short8 vb = *(short8*)&Vt[tn * 16 + l15][kk * 32 + quad * 8];
                    o_acc[tn] = __builtin_amdgcn_mfma_f32_16x16x32_bf16(pa, vb, o_acc[tn], 0, 0, 0);
                }
            }
        }
#pragma unroll
        for (int r = 0; r < 4; ++r) {
            float inv = 0.5f / fmaxf(l_acc[r], 1e-30f);
#pragma unroll
            for (int tn = 0; tn < 4; ++tn)
                result[tn][r] += o_acc[tn][r] * inv;
        }
    }

#pragma unroll
    for (int r = 0; r < 4; ++r) {
        int srow = q0 + wave * 16 + quad * 4 + r;
        int m = srow * BSZ + b;
#pragma unroll
        for (int tn = 0; tn < 4; ++tn) {
            int dcol = h * HD + tn * 16 + l15;
            out[(size_t)m * DIM + dcol] = f2b(result[tn][r]);
        }
    }
}

// ---------------------------------------------------------------------------
extern "C" void kernel_launch(void* const* d_in, const int* in_sizes, int n_in,
                              void* d_out, int out_size, void* d_ws, size_t ws_size,
                              hipStream_t stream) {
    (void)in_sizes; (void)n_in; (void)out_size; (void)ws_size;
    const float* query = (const float*)d_in[0];
    const float* Wq_b  = (const float*)d_in[1];
    const float* bq_b  = (const float*)d_in[2];
    const float* Wk_b  = (const float*)d_in[3];
    const float* bk_b  = (const float*)d_in[4];
    const float* Wq_g  = (const float*)d_in[5];
    const float* bq_g  = (const float*)d_in[6];
    const float* Wk_g  = (const float*)d_in[7];
    const float* bk_g  = (const float*)d_in[8];
    const float* Wv    = (const float*)d_in[9];
    const float* bv    = (const float*)d_in[10];
    const float* Wo    = (const float*)d_in[11];
    const float* bo    = (const float*)d_in[12];
    float* out = (float*)d_out;

    const size_t NQ = (size_t)BSZ * NH * SEQ * HD;   // 4194304
    const size_t NP = (size_t)BSZ * NH * PN * HD;    // 524288
    bf16* qbf      = (bf16*)d_ws;                    // 4M
    bf16* wbf      = qbf + NQ;                       // 6M   [q_b,k_b,v,q_g,k_g,o]
    bf16* phrasebf = wbf + (size_t)6 * DIM * DIM;    // 512K
    bf16* q_b      = phrasebf + (size_t)PN * BSZ * DIM;
    bf16* k_b      = q_b + NQ;
    bf16* vT       = k_b + NQ;                       // [bh][hd][s]
    bf16* q_g      = vT + NQ;
    bf16* k_g      = q_g + NQ;                       // [bh][p][hd]
    bf16* gvT      = k_g + NP;                       // [bh][hd][p]
    bf16* attn_bf  = gvT + NP;                       // [m][dcol]
    float* bias_pack = (float*)(attn_bf + NQ);       // 6*1024 fp32
    // total ws use: ~64 MB

    const int QV = (SEQ * BSZ * DIM) / 8, WV6 = 6 * (DIM * DIM) / 8;
    convert_kernel<<<(QV + WV6) / 256, 256, 0, stream>>>(
        query, Wq_b, Wk_b, Wv, Wq_g, Wk_g, Wo, qbf, wbf);
    bias_pack_kernel<<<24, 256, 0, stream>>>(bq_b, bk_b, bv, bq_g, bk_g, bo, bias_pack);
    phrase_max_kernel<<<(PN * BSZ * DIM) / 256, 256, 0, stream>>>(query, phrasebf);

    dim3 gp((SEQ * BSZ) / 128, DIM / 128, 5);
    gemm_proj<<<gp, 256, 0, stream>>>(qbf, phrasebf, wbf, bias_pack,
                                      q_b, k_b, vT, q_g, k_g);

    gauss_v_kernel<<<BSZ * NH * HD, PN, 0, stream>>>(vT, gvT);

    dim3 g3(SEQ / 64, BSZ * NH);
    attn_kernel<<<g3, 256, 0, stream>>>(q_b, k_b, vT, q_g, k_g, gvT, attn_bf);

    dim3 gf((SEQ * BSZ) / 128, DIM / 128);
    gemm_final<<<gf, 256, 0, stream>>>(attn_bf, wbf, bias_pack, out);
}